// Round 3
// baseline (272.642 us; speedup 1.0000x reference)
//
#include <hip/hip_runtime.h>

// out[i]        = p[i]                      i in [0, SIZE)
// out[SIZE + i] = w[i] * selu(p[i]) + q[i]
//
// Round-5: keep the single-dispatch block-role split (round-4: neutral vs
// 2-dispatch), add a x4 unroll to attack the measured limiter.
// Evidence (round-4 counters): 2.8 TB/s HBM (34% peak), VALUBusy 4%,
// occupancy 62% -> latency/MLP-bound, not BW- or compute-bound.
// Each selu thread now issues 12 independent dwordx4 loads (192 B/lane)
// before its first s_waitcnt; copy threads issue 4.
// N.B. round-3's "no unroll" finding was on the old 5-stream fused shape;
// re-tested here deliberately on the 4-stream role-split shape.

typedef float v4f __attribute__((ext_vector_type(4)));

#ifndef UNROLL
#define UNROLL 4
#endif

__global__ void __launch_bounds__(256)
fused_roles_u4(const v4f* __restrict__ x4, const v4f* __restrict__ w4,
               v4f* __restrict__ out4, int n4) {
    const int bid  = blockIdx.x;
    const int role = bid & 1;                 // 0: copy half, 1: selu half
    const int tile = (bid >> 1) * (256 * UNROLL);
    const int base = tile + threadIdx.x;

    // n4 = 4194304 is divisible by 256*UNROLL=1024, so every block is full;
    // keep a cheap uniform guard for generality.
    if (tile + 256 * UNROLL > n4) {
        for (int u = 0; u < UNROLL; ++u) {
            int i = base + u * 256;
            if (i >= n4) break;
            if (role == 0) {
                out4[i] = x4[i];
            } else {
                const float scale = 1.0507009873554805f;
                const float alpha = 1.6732632423543773f;
                v4f p = x4[i], q = x4[n4 + i], w = w4[i];
                v4f r;
                for (int c = 0; c < 4; ++c) {
                    float pv = p[c];
                    float s  = pv > 0.f ? pv : alpha * (__expf(pv) - 1.f);
                    r[c] = w[c] * (scale * s) + q[c];
                }
                out4[n4 + i] = r;
            }
        }
        return;
    }

    if (role == 0) {
        // copy: 4 independent loads in flight, then 4 stores
        v4f p[UNROLL];
#pragma unroll
        for (int u = 0; u < UNROLL; ++u) p[u] = x4[base + u * 256];
#pragma unroll
        for (int u = 0; u < UNROLL; ++u) out4[base + u * 256] = p[u];
    } else {
        // selu-residual: 12 independent loads in flight, then compute+store
        const float scale = 1.0507009873554805f;
        const float alpha = 1.6732632423543773f;

        v4f p[UNROLL], q[UNROLL], w[UNROLL];
#pragma unroll
        for (int u = 0; u < UNROLL; ++u) {
            int i = base + u * 256;
            p[u] = x4[i];
            q[u] = x4[n4 + i];
            w[u] = w4[i];
        }
#pragma unroll
        for (int u = 0; u < UNROLL; ++u) {
            int i = base + u * 256;
            v4f r;
#pragma unroll
            for (int c = 0; c < 4; ++c) {
                float pv = p[u][c];
                float s  = pv > 0.f ? pv : alpha * (__expf(pv) - 1.f);
                r[c] = w[u][c] * (scale * s) + q[u][c];
            }
            out4[n4 + i] = r;
        }
    }
}

extern "C" void kernel_launch(void* const* d_in, const int* in_sizes, int n_in,
                              void* d_out, int out_size, void* d_ws, size_t ws_size,
                              hipStream_t stream) {
    const v4f* x4 = (const v4f*)d_in[0];
    const v4f* w4 = (const v4f*)d_in[1];
    v4f* out4 = (v4f*)d_out;

    int size = in_sizes[1];      // SIZE = N/2 = 16777216
    int n4 = size / 4;           // 4194304 float4 per half

    int block = 256;
    int per_block = block * UNROLL;                       // 1024 float4
    int blocks_per_role = (n4 + per_block - 1) / per_block;  // 4096
    int grid = 2 * blocks_per_role;                       // 8192, roles interleaved

    fused_roles_u4<<<grid, block, 0, stream>>>(x4, w4, out4, n4);
}